// Round 3
// baseline (594.726 us; speedup 1.0000x reference)
//
#include <hip/hip_runtime.h>
#include <hip/hip_bf16.h>

#define N_PTS 8192
#define KNN 8

// ---------------------------------------------------------------------------
// KNN stage 1: per (query, partition-of-1024) wave, exact top-8 via
// threshold-first selection. One query per LANE; candidate index is
// wave-uniform (derived from blockIdx + loop counter only) so candidate
// coordinate loads compile to scalar s_load broadcasts (no LDS, no per-lane
// vmem). Phase 1: 32 branchless rotating bucket-minima. Threshold t = 8th
// smallest bucket-min (valid upper bound on the true 8th distance: every
// bucket holding a top-8 element has min <= d(8); at most 8 such buckets).
// Phase 2: collect d2 <= t (expected ~9.1 +- 1.1 entries, cap 16, exact
// fallback on overflow) then exact top-8 over packed (d2bits<<32|idx) keys.
// f32 exact-difference distances: round-1 f64 run passed identically, and
// this form is ~30x tighter than the reference's cancellation-prone formula.
// ---------------------------------------------------------------------------
__global__ __launch_bounds__(64) void knn_partial(const float* __restrict__ pos,
                                                  unsigned long long* __restrict__ partial)
{
    __shared__ unsigned long long buf[64 * 17];   // 16 slots + 1 trash, padded
    const int lane  = threadIdx.x;
    const int batch = blockIdx.x >> 10;           // 1024 blocks per batch
    const int qg    = (blockIdx.x >> 3) & 127;    // query group of 64
    const int p     = blockIdx.x & 7;             // candidate partition
    const float* bpos = pos + (long)batch * N_PTS * 3;
    const int q_in_b = qg * 64 + lane;

    const float qx = bpos[q_in_b * 3 + 0];
    const float qy = bpos[q_in_b * 3 + 1];
    const float qz = bpos[q_in_b * 3 + 2];

    const float* cp = bpos + p * 1024 * 3;        // uniform base

    // ---- phase 1: branchless bucket minima -------------------------------
    float bmin[32];
#pragma unroll
    for (int j = 0; j < 32; ++j) bmin[j] = 3.0e38f;

    for (int i = 0; i < 1024; i += 32) {
#pragma unroll
        for (int j = 0; j < 32; ++j) {
            const float cx = cp[(i + j) * 3 + 0];
            const float cy = cp[(i + j) * 3 + 1];
            const float cz = cp[(i + j) * 3 + 2];
            const float dx = cx - qx, dy = cy - qy, dz = cz - qz;
            const float d2 = fmaf(dx, dx, fmaf(dy, dy, dz * dz));
            bmin[j] = fminf(bmin[j], d2);
        }
    }

    // ---- threshold: 8th smallest of 32 bucket minima (branchless) --------
    float t8[8];
#pragma unroll
    for (int j = 0; j < 8; ++j) t8[j] = 3.0e38f;
#pragma unroll
    for (int i = 0; i < 32; ++i) {
        float x = bmin[i];
#pragma unroll
        for (int j = 0; j < 8; ++j) {
            const float lo = fminf(t8[j], x);
            const float hi = fmaxf(t8[j], x);
            t8[j] = lo; x = hi;
        }
    }
    const float t = t8[7];

    // ---- phase 2: collect candidates below threshold ---------------------
    int cnt = 0;
    for (int i = 0; i < 1024; i += 8) {
#pragma unroll
        for (int j = 0; j < 8; ++j) {
            const float cx = cp[(i + j) * 3 + 0];
            const float cy = cp[(i + j) * 3 + 1];
            const float cz = cp[(i + j) * 3 + 2];
            const float dx = cx - qx, dy = cy - qy, dz = cz - qz;
            const float d2 = fmaf(dx, dx, fmaf(dy, dy, dz * dz));
            if (d2 <= t) {
                const int slot = cnt < 16 ? cnt : 16;   // slot 16 = trash
                buf[lane * 17 + slot] =
                    ((unsigned long long)__float_as_uint(d2) << 32)
                    | (unsigned)(p * 1024 + i + j);
                ++cnt;
            }
        }
    }

    // ---- exact top-8 over collected (or rare exact fallback) -------------
    unsigned long long best[8];
#pragma unroll
    for (int j = 0; j < 8; ++j) best[j] = ~0ULL;

    if (cnt <= 16) {
        for (int u = 0; u < cnt; ++u) {
            unsigned long long x = buf[lane * 17 + u];
#pragma unroll
            for (int j = 0; j < 8; ++j) {
                const unsigned long long lo = x < best[j] ? x : best[j];
                const unsigned long long hi = x < best[j] ? best[j] : x;
                best[j] = lo; x = hi;
            }
        }
    } else {
        // statistically-never exact rescan (correctness guarantee)
        for (int i = 0; i < 1024; ++i) {
            const float cx = cp[i * 3 + 0], cy = cp[i * 3 + 1], cz = cp[i * 3 + 2];
            const float dx = cx - qx, dy = cy - qy, dz = cz - qz;
            const float d2 = fmaf(dx, dx, fmaf(dy, dy, dz * dz));
            unsigned long long x =
                ((unsigned long long)__float_as_uint(d2) << 32)
                | (unsigned)(p * 1024 + i);
            if (x < best[7]) {
#pragma unroll
                for (int j = 0; j < 8; ++j) {
                    const unsigned long long lo = x < best[j] ? x : best[j];
                    const unsigned long long hi = x < best[j] ? best[j] : x;
                    best[j] = lo; x = hi;
                }
            }
        }
    }

    const int qglob = batch * N_PTS + q_in_b;
#pragma unroll
    for (int j = 0; j < 8; ++j)
        partial[(long)(p * 8 + j) * 16384 + qglob] = best[j];   // coalesced
}

// ---------------------------------------------------------------------------
// KNN stage 2: merge 8 partitions x 8 pairs per query (u64 keys compare as
// (d2, idx) lexicographic). Slot-major layout -> coalesced loads.
// ---------------------------------------------------------------------------
__global__ __launch_bounds__(256) void knn_merge(const unsigned long long* __restrict__ partial,
                                                 int* __restrict__ idxo)
{
    const int q = blockIdx.x * 256 + threadIdx.x;   // 0..16383
    unsigned long long best[8];
#pragma unroll
    for (int j = 0; j < 8; ++j) best[j] = ~0ULL;
    for (int s = 0; s < 64; ++s) {
        unsigned long long x = partial[(long)s * 16384 + q];
        if (x < best[7]) {
#pragma unroll
            for (int j = 0; j < 8; ++j) {
                const unsigned long long lo = x < best[j] ? x : best[j];
                const unsigned long long hi = x < best[j] ? best[j] : x;
                best[j] = lo; x = hi;
            }
        }
    }
#pragma unroll
    for (int j = 0; j < 8; ++j)
        idxo[(long)q * 8 + j] = (int)(best[j] & 0xFFFFFFFFu);
}

// ---------------------------------------------------------------------------
// fp32 SGEMM: C[M,N] = A[M,K] * B[K,N] (+ bias[N]). 128x128 tile, BK=16,
// 256 threads, 8x8 micro-tile (2x2 blocks of float4): 64 fma per 4 ds_read_b128.
// ---------------------------------------------------------------------------
__global__ __launch_bounds__(256) void sgemm128(const float* __restrict__ A,
                                                const float* __restrict__ B,
                                                const float* __restrict__ bias,
                                                float* __restrict__ C,
                                                int M, int N, int Kd)
{
    __shared__ float As[16][132];   // [k][m] transposed, +4 pad
    __shared__ float Bs[16][128];   // [k][n]

    const int tid = threadIdx.x;
    const int tx = tid & 15;
    const int ty = tid >> 4;
    const int bx = blockIdx.x;
    const int by = blockIdx.y;

    const int arow  = tid >> 1;          // 0..127
    const int acol8 = (tid & 1) * 8;     // 0 or 8
    const int brow  = tid >> 4;          // 0..15
    const int bcol  = (tid & 15) * 4;    // 0..60

    const float* Ap = A + (long)(by * 128 + arow) * Kd + acol8;
    const float* Bp = B + (long)brow * N + bx * 128 + bcol;

    float acc[8][8];
#pragma unroll
    for (int i = 0; i < 8; ++i)
#pragma unroll
        for (int j = 0; j < 8; ++j) acc[i][j] = 0.f;

    for (int kt = 0; kt < Kd; kt += 16) {
        const float4 av0 = *(const float4*)(Ap + kt);
        const float4 av1 = *(const float4*)(Ap + kt + 4);
        const float4 bv0 = *(const float4*)(Bp + (long)kt * N);
        const float4 bv1 = *(const float4*)(Bp + (long)kt * N + 64);
        As[acol8 + 0][arow] = av0.x;
        As[acol8 + 1][arow] = av0.y;
        As[acol8 + 2][arow] = av0.z;
        As[acol8 + 3][arow] = av0.w;
        As[acol8 + 4][arow] = av1.x;
        As[acol8 + 5][arow] = av1.y;
        As[acol8 + 6][arow] = av1.z;
        As[acol8 + 7][arow] = av1.w;
        *(float4*)&Bs[brow][bcol] = bv0;
        *(float4*)&Bs[brow][bcol + 64] = bv1;
        __syncthreads();
#pragma unroll
        for (int k = 0; k < 16; ++k) {
            const float4 a0 = *(const float4*)&As[k][ty * 4];
            const float4 a1 = *(const float4*)&As[k][ty * 4 + 64];
            const float4 b0 = *(const float4*)&Bs[k][tx * 4];
            const float4 b1 = *(const float4*)&Bs[k][tx * 4 + 64];
            const float ar[8] = {a0.x, a0.y, a0.z, a0.w, a1.x, a1.y, a1.z, a1.w};
            const float br[8] = {b0.x, b0.y, b0.z, b0.w, b1.x, b1.y, b1.z, b1.w};
#pragma unroll
            for (int i = 0; i < 8; ++i)
#pragma unroll
                for (int j = 0; j < 8; ++j)
                    acc[i][j] = fmaf(ar[i], br[j], acc[i][j]);
        }
        __syncthreads();
    }

    float4 bb0 = make_float4(0.f, 0.f, 0.f, 0.f);
    float4 bb1 = bb0;
    if (bias) {
        bb0 = *(const float4*)(bias + bx * 128 + tx * 4);
        bb1 = *(const float4*)(bias + bx * 128 + tx * 4 + 64);
    }
#pragma unroll
    for (int ih = 0; ih < 2; ++ih) {
#pragma unroll
        for (int i = 0; i < 4; ++i) {
            const int row = by * 128 + ty * 4 + ih * 64 + i;
            float* crow = C + (long)row * N + bx * 128;
            float4 o0, o1;
            o0.x = acc[ih * 4 + i][0] + bb0.x;
            o0.y = acc[ih * 4 + i][1] + bb0.y;
            o0.z = acc[ih * 4 + i][2] + bb0.z;
            o0.w = acc[ih * 4 + i][3] + bb0.w;
            o1.x = acc[ih * 4 + i][4] + bb1.x;
            o1.y = acc[ih * 4 + i][5] + bb1.y;
            o1.z = acc[ih * 4 + i][6] + bb1.z;
            o1.w = acc[ih * 4 + i][7] + bb1.w;
            *(float4*)(crow + tx * 4) = o0;
            *(float4*)(crow + tx * 4 + 64) = o1;
        }
    }
}

// ---------------------------------------------------------------------------
// Fused KNN attention. One wave per query. Phase 1: lane=(h,k) computes one
// q.k dot (64-long, float4 loads), shfl softmax over k-groups of 8.
// Phase 2: lane=d, coalesced v gather, weighted sum, write out.
// outp may alias qall (q fully consumed before the barrier; one wave per row).
// ---------------------------------------------------------------------------
__global__ __launch_bounds__(256) void attn_kernel(const float* qall,
                                                   const float* __restrict__ kvall,
                                                   const int* __restrict__ idxp,
                                                   float* outp)
{
    __shared__ float attn_s[4][8][8];
    const int wave = threadIdx.x >> 6;
    const int lane = threadIdx.x & 63;
    const int g = blockIdx.x * 4 + wave;     // query 0..16383
    const int b = g >> 13;
    const int* myidx = idxp + (long)g * 8;

    const int h = lane >> 3;
    const int k = lane & 7;
    const int j = myidx[k];
    const float* qrow = qall + (long)g * 512 + h * 64;
    const float* krow = kvall + ((long)(b * N_PTS + j)) * 1024 + h * 64;

    float dot = 0.f;
#pragma unroll
    for (int d4 = 0; d4 < 64; d4 += 4) {
        const float4 qv = *(const float4*)(qrow + d4);
        const float4 kv = *(const float4*)(krow + d4);
        dot = fmaf(qv.x, kv.x, dot);
        dot = fmaf(qv.y, kv.y, dot);
        dot = fmaf(qv.z, kv.z, dot);
        dot = fmaf(qv.w, kv.w, dot);
    }
    dot *= 0.125f;                            // DH^-0.5

    float m = dot;
#pragma unroll
    for (int off = 1; off < 8; off <<= 1)
        m = fmaxf(m, __shfl_xor(m, off, 8));
    const float e = __expf(dot - m);
    float ssum = e;
#pragma unroll
    for (int off = 1; off < 8; off <<= 1)
        ssum += __shfl_xor(ssum, off, 8);
    attn_s[wave][h][k] = e / ssum;
    __syncthreads();                          // also drains q loads before aliased writes

    const int d = lane;
    float o[8] = {0.f, 0.f, 0.f, 0.f, 0.f, 0.f, 0.f, 0.f};
#pragma unroll
    for (int kk = 0; kk < 8; ++kk) {
        const int jj = myidx[kk];
        const float* vrow = kvall + ((long)(b * N_PTS + jj)) * 1024 + 512 + d;
#pragma unroll
        for (int hh = 0; hh < 8; ++hh)
            o[hh] = fmaf(attn_s[wave][hh][kk], vrow[hh * 64], o[hh]);
    }
    float* orow = outp + (long)g * 512 + d;
#pragma unroll
    for (int hh = 0; hh < 8; ++hh)
        orow[hh * 64] = o[hh];
}

// ---------------------------------------------------------------------------
extern "C" void kernel_launch(void* const* d_in, const int* in_sizes, int n_in,
                              void* d_out, int out_size, void* d_ws, size_t ws_size,
                              hipStream_t stream)
{
    const float* x    = (const float*)d_in[0];  // [2,8192,256]
    const float* pos  = (const float*)d_in[1];  // [2,8192,3]
    const float* Wq   = (const float*)d_in[2];  // [256,512]
    const float* Wkv  = (const float*)d_in[3];  // [256,1024]
    const float* Wout = (const float*)d_in[4];  // [512,256]
    const float* bout = (const float*)d_in[5];  // [256]
    float* out = (float*)d_out;                 // [2,8192,256] f32

    // workspace layout (96.5 MB total):
    int*   idxp  = (int*)d_ws;                       // 131072 ints (512 KB)
    float* qall  = (float*)d_ws + 131072;            // 16384x512 f32 (32 MB)
    float* kvall = qall + (long)16384 * 512;         // 16384x1024 f32 (64 MB)
    // knn scratch: lives in kvall region, fully consumed before sgemm_kv writes it
    unsigned long long* partial = (unsigned long long*)kvall;   // 64*16384*8 = 8.4 MB

    const int M = 16384;

    knn_partial<<<2048, 64, 0, stream>>>(pos, partial);
    knn_merge<<<64, 256, 0, stream>>>(partial, idxp);
    sgemm128<<<dim3(512 / 128, M / 128), 256, 0, stream>>>(x, Wq, nullptr, qall, M, 512, 256);
    sgemm128<<<dim3(1024 / 128, M / 128), 256, 0, stream>>>(x, Wkv, nullptr, kvall, M, 1024, 256);
    attn_kernel<<<M / 4, 256, 0, stream>>>(qall, kvall, idxp, qall);   // in-place over qall
    sgemm128<<<dim3(256 / 128, M / 128), 256, 0, stream>>>(qall, Wout, bout, out, M, 256, 512);
}

// Round 4
// 404.967 us; speedup vs baseline: 1.4686x; 1.4686x over previous
//
#include <hip/hip_runtime.h>
#include <hip/hip_bf16.h>

#define N_PTS 8192
#define KNN 8

typedef __attribute__((ext_vector_type(8))) short short8;
typedef __attribute__((ext_vector_type(4))) float float4v;

// f32 -> bf16 round-to-nearest-even (finite inputs only)
static __device__ __forceinline__ short f2bf(float f) {
    unsigned u = __float_as_uint(f);
    unsigned r = (u + 0x7FFFu + ((u >> 16) & 1u)) >> 16;
    return (short)r;
}

// ---------------------------------------------------------------------------
// KNN stage 1 v3: 1024 blocks x 256 threads. One query per THREAD; block =
// (query-group of 256) x (candidate partition of 512). Candidates staged in
// LDS as SoA (sx/sy/sz); inner loop reads float4 at a wave-uniform address
// (LDS broadcast, conflict-free). Phase 1: branchless 32 rotating bucket
// minima (7 VALU/candidate). Threshold t = 8th smallest bucket min (upper
// bound on true d(8): the top-8 occupy <=8 buckets, each with min <= d(8)).
// Phase 2: rescan, collect d2 <= t (E[count]~9, cap 16; exact-rescan
// fallback preserves correctness). Exact top-8 over packed (d2bits<<32|idx).
// f32 exact-difference distances (see round-2 note: provably tighter than
// the reference's cancellation-prone formula; f64 run passed identically).
// ---------------------------------------------------------------------------
__global__ __launch_bounds__(256) void knn_partial(const float* __restrict__ pos,
                                                   unsigned long long* __restrict__ partial)
{
    __shared__ float sx[512], sy[512], sz[512];           // 6 KB SoA
    __shared__ unsigned long long buf[256][17];           // 34 KB collect

    const int tid = threadIdx.x;
    const int p   = blockIdx.x & 15;           // candidate partition 0..15
    const int qg  = blockIdx.x >> 4;           // query group 0..63
    const int batch = qg >> 5;
    const int q_in_b = (qg & 31) * 256 + tid;
    const float* bpos = pos + (long)batch * N_PTS * 3;

    // stage partition p (512 candidates, AoS float3 -> SoA) -- 128 threads
    if (tid < 128) {
        const float* src = bpos + (p * 512 + tid * 4) * 3;   // 48B-aligned
        const float4 f0 = *(const float4*)(src);
        const float4 f1 = *(const float4*)(src + 4);
        const float4 f2 = *(const float4*)(src + 8);
        const int c0 = tid * 4;
        *(float4*)&sx[c0] = make_float4(f0.x, f0.w, f1.z, f2.y);
        *(float4*)&sy[c0] = make_float4(f0.y, f1.x, f1.w, f2.z);
        *(float4*)&sz[c0] = make_float4(f0.z, f1.y, f2.x, f2.w);
    }
    __syncthreads();

    const float qx = bpos[q_in_b * 3 + 0];
    const float qy = bpos[q_in_b * 3 + 1];
    const float qz = bpos[q_in_b * 3 + 2];

    const float4* vx = (const float4*)sx;
    const float4* vy = (const float4*)sy;
    const float4* vz = (const float4*)sz;

    // ---- phase 1: branchless bucket minima -------------------------------
    float bmin[32];
#pragma unroll
    for (int j = 0; j < 32; ++j) bmin[j] = 3.0e38f;

    for (int base = 0; base < 128; base += 8) {
#pragma unroll
        for (int g = 0; g < 8; ++g) {
            const float4 cx = vx[base + g];
            const float4 cy = vy[base + g];
            const float4 cz = vz[base + g];
            {
                const float dx = cx.x - qx, dy = cy.x - qy, dz = cz.x - qz;
                bmin[g * 4 + 0] = fminf(bmin[g * 4 + 0], fmaf(dx, dx, fmaf(dy, dy, dz * dz)));
            }
            {
                const float dx = cx.y - qx, dy = cy.y - qy, dz = cz.y - qz;
                bmin[g * 4 + 1] = fminf(bmin[g * 4 + 1], fmaf(dx, dx, fmaf(dy, dy, dz * dz)));
            }
            {
                const float dx = cx.z - qx, dy = cy.z - qy, dz = cz.z - qz;
                bmin[g * 4 + 2] = fminf(bmin[g * 4 + 2], fmaf(dx, dx, fmaf(dy, dy, dz * dz)));
            }
            {
                const float dx = cx.w - qx, dy = cy.w - qy, dz = cz.w - qz;
                bmin[g * 4 + 3] = fminf(bmin[g * 4 + 3], fmaf(dx, dx, fmaf(dy, dy, dz * dz)));
            }
        }
    }

    // ---- threshold: 8th smallest of 32 bucket minima (branchless net) ----
    float t8[8];
#pragma unroll
    for (int j = 0; j < 8; ++j) t8[j] = 3.0e38f;
#pragma unroll
    for (int i = 0; i < 32; ++i) {
        float x = bmin[i];
#pragma unroll
        for (int j = 0; j < 8; ++j) {
            const float lo = fminf(t8[j], x);
            const float hi = fmaxf(t8[j], x);
            t8[j] = lo; x = hi;
        }
    }
    const float t = t8[7];

    // ---- phase 2: collect candidates below threshold ---------------------
    int cnt = 0;
    for (int base = 0; base < 128; ++base) {
        const float4 cx = vx[base];
        const float4 cy = vy[base];
        const float4 cz = vz[base];
#pragma unroll
        for (int j = 0; j < 4; ++j) {
            const float ccx = j == 0 ? cx.x : j == 1 ? cx.y : j == 2 ? cx.z : cx.w;
            const float ccy = j == 0 ? cy.x : j == 1 ? cy.y : j == 2 ? cy.z : cy.w;
            const float ccz = j == 0 ? cz.x : j == 1 ? cz.y : j == 2 ? cz.z : cz.w;
            const float dx = ccx - qx, dy = ccy - qy, dz = ccz - qz;
            const float d2 = fmaf(dx, dx, fmaf(dy, dy, dz * dz));
            if (d2 <= t) {
                buf[tid][cnt < 16 ? cnt : 16] =
                    ((unsigned long long)__float_as_uint(d2) << 32)
                    | (unsigned)(p * 512 + base * 4 + j);
                ++cnt;
            }
        }
    }

    // ---- exact top-8 over collected (or rare exact fallback) -------------
    unsigned long long best[8];
#pragma unroll
    for (int j = 0; j < 8; ++j) best[j] = ~0ULL;

    if (cnt <= 16) {
        for (int u = 0; u < cnt; ++u) {
            unsigned long long x = buf[tid][u];
#pragma unroll
            for (int j = 0; j < 8; ++j) {
                const unsigned long long lo = x < best[j] ? x : best[j];
                const unsigned long long hi = x < best[j] ? best[j] : x;
                best[j] = lo; x = hi;
            }
        }
    } else {
        for (int i = 0; i < 512; ++i) {     // statistically-never fallback
            const float dx = sx[i] - qx, dy = sy[i] - qy, dz = sz[i] - qz;
            const float d2 = fmaf(dx, dx, fmaf(dy, dy, dz * dz));
            unsigned long long x =
                ((unsigned long long)__float_as_uint(d2) << 32)
                | (unsigned)(p * 512 + i);
            if (x < best[7]) {
#pragma unroll
                for (int j = 0; j < 8; ++j) {
                    const unsigned long long lo = x < best[j] ? x : best[j];
                    const unsigned long long hi = x < best[j] ? best[j] : x;
                    best[j] = lo; x = hi;
                }
            }
        }
    }

    const long qglob = (long)batch * N_PTS + q_in_b;
#pragma unroll
    for (int j = 0; j < 8; ++j)
        partial[(long)(p * 8 + j) * 16384 + qglob] = best[j];   // coalesced
}

// ---------------------------------------------------------------------------
// KNN stage 2: merge 16 partitions x 8 pairs per query. Slot-major layout ->
// coalesced loads. u64 keys compare as (d2, idx) lexicographic.
// ---------------------------------------------------------------------------
__global__ __launch_bounds__(256) void knn_merge(const unsigned long long* __restrict__ partial,
                                                 int* __restrict__ idxo)
{
    const int q = blockIdx.x * 256 + threadIdx.x;   // 0..16383
    unsigned long long best[8];
#pragma unroll
    for (int j = 0; j < 8; ++j) best[j] = ~0ULL;
    for (int s = 0; s < 128; ++s) {
        unsigned long long x = partial[(long)s * 16384 + q];
        if (x < best[7]) {
#pragma unroll
            for (int j = 0; j < 8; ++j) {
                const unsigned long long lo = x < best[j] ? x : best[j];
                const unsigned long long hi = x < best[j] ? best[j] : x;
                best[j] = lo; x = hi;
            }
        }
    }
#pragma unroll
    for (int j = 0; j < 8; ++j)
        idxo[(long)q * 8 + j] = (int)(best[j] & 0xFFFFFFFFu);
}

// ---------------------------------------------------------------------------
// bf16 MFMA GEMM: C[M,N] f32 = A[M,K] * B[K,N], inputs converted f32->bf16
// (RNE) during LDS staging. 128x128 tile, BK=32, 256 thr = 4 waves in 2x2
// (each wave 64x64 = 4x4 grid of 16x16x32 MFMA). Fragment layouts per
// verified m89/m91/m120: A[m=lane&15][k=quad*8+j]; B[k=quad*8+j][n=lane&15]
// (stored [n][k8] blocked); C/D row=quad*4+r, col=lane&15.
// ABF16: A is already bf16 (lda in elements).
// ---------------------------------------------------------------------------
template<int ABF16>
__global__ __launch_bounds__(256) void gemm_bf16(const void* __restrict__ A_,
                                                 const float* __restrict__ B,
                                                 float* __restrict__ C,
                                                 int N, int Kd, int lda)
{
    __shared__ short As[4][128][8];   // [k>>3][m][k&7]  8 KB
    __shared__ short Bs[4][128][8];   // [k>>3][n][k&7]  8 KB

    const int tid  = threadIdx.x;
    const int lane = tid & 63;
    const int wv   = tid >> 6;
    const int quad = lane >> 4;
    const int l15  = lane & 15;
    const int m0 = blockIdx.y * 128;
    const int n0 = blockIdx.x * 128;
    const int mh = (wv & 1) * 64, nh = (wv >> 1) * 64;

    const int sm  = tid >> 1;             // A staging row 0..127
    const int skh = (tid & 1) * 16;       // A staging k-offset {0,16}
    const int sn  = tid & 127;            // B staging col
    const int skb = (tid >> 7) * 16;      // B staging k-offset {0,16}

    float4v acc[4][4];
#pragma unroll
    for (int i = 0; i < 4; ++i)
#pragma unroll
        for (int j = 0; j < 4; ++j) acc[i][j] = (float4v)(0.f);

    for (int k0 = 0; k0 < Kd; k0 += 32) {
        // ---- stage A tile ----
        if (ABF16) {
            const short* Ab = (const short*)A_;
            const short8* src = (const short8*)(Ab + (long)(m0 + sm) * lda + k0 + skh);
            *(short8*)&As[skh >> 3][sm][0] = src[0];
            *(short8*)&As[(skh >> 3) + 1][sm][0] = src[1];
        } else {
            const float* Af = (const float*)A_;
            const float* ap = Af + (long)(m0 + sm) * lda + k0 + skh;
            const float4 a0 = *(const float4*)ap;
            const float4 a1 = *(const float4*)(ap + 4);
            const float4 a2 = *(const float4*)(ap + 8);
            const float4 a3 = *(const float4*)(ap + 12);
            short8 w0 = {f2bf(a0.x), f2bf(a0.y), f2bf(a0.z), f2bf(a0.w),
                         f2bf(a1.x), f2bf(a1.y), f2bf(a1.z), f2bf(a1.w)};
            short8 w1 = {f2bf(a2.x), f2bf(a2.y), f2bf(a2.z), f2bf(a2.w),
                         f2bf(a3.x), f2bf(a3.y), f2bf(a3.z), f2bf(a3.w)};
            *(short8*)&As[skh >> 3][sm][0] = w0;
            *(short8*)&As[(skh >> 3) + 1][sm][0] = w1;
        }
        // ---- stage B tile (transposed into [n][k8] blocks) ----
        {
            const float* bp = B + (long)(k0 + skb) * N + n0 + sn;
            short v[16];
#pragma unroll
            for (int kk = 0; kk < 16; ++kk)
                v[kk] = f2bf(bp[(long)kk * N]);      // wave-coalesced per kk
            short8 w0 = {v[0], v[1], v[2], v[3], v[4], v[5], v[6], v[7]};
            short8 w1 = {v[8], v[9], v[10], v[11], v[12], v[13], v[14], v[15]};
            *(short8*)&Bs[skb >> 3][sn][0] = w0;
            *(short8*)&Bs[(skb >> 3) + 1][sn][0] = w1;
        }
        __syncthreads();

        short8 af[4], bfv[4];
#pragma unroll
        for (int i = 0; i < 4; ++i)
            af[i] = *(const short8*)&As[quad][mh + i * 16 + l15][0];
#pragma unroll
        for (int j = 0; j < 4; ++j)
            bfv[j] = *(const short8*)&Bs[quad][nh + j * 16 + l15][0];
#pragma unroll
        for (int i = 0; i < 4; ++i)
#pragma unroll
            for (int j = 0; j < 4; ++j)
                acc[i][j] = __builtin_amdgcn_mfma_f32_16x16x32_bf16(af[i], bfv[j], acc[i][j], 0, 0, 0);
        __syncthreads();
    }

#pragma unroll
    for (int i = 0; i < 4; ++i)
#pragma unroll
        for (int j = 0; j < 4; ++j) {
            const int col = n0 + nh + j * 16 + l15;
#pragma unroll
            for (int r = 0; r < 4; ++r) {
                const int row = m0 + mh + i * 16 + quad * 4 + r;
                C[(long)row * N + col] = acc[i][j][r];
            }
        }
}

// ---------------------------------------------------------------------------
// fp32 SGEMM (kept for out-projection: protects error budget). 128x128 tile.
// ---------------------------------------------------------------------------
__global__ __launch_bounds__(256) void sgemm128(const float* __restrict__ A,
                                                const float* __restrict__ B,
                                                const float* __restrict__ bias,
                                                float* __restrict__ C,
                                                int M, int N, int Kd)
{
    __shared__ float As[16][132];
    __shared__ float Bs[16][128];

    const int tid = threadIdx.x;
    const int tx = tid & 15;
    const int ty = tid >> 4;
    const int bx = blockIdx.x;
    const int by = blockIdx.y;

    const int arow  = tid >> 1;
    const int acol8 = (tid & 1) * 8;
    const int brow  = tid >> 4;
    const int bcol  = (tid & 15) * 4;

    const float* Ap = A + (long)(by * 128 + arow) * Kd + acol8;
    const float* Bp = B + (long)brow * N + bx * 128 + bcol;

    float acc[8][8];
#pragma unroll
    for (int i = 0; i < 8; ++i)
#pragma unroll
        for (int j = 0; j < 8; ++j) acc[i][j] = 0.f;

    for (int kt = 0; kt < Kd; kt += 16) {
        const float4 av0 = *(const float4*)(Ap + kt);
        const float4 av1 = *(const float4*)(Ap + kt + 4);
        const float4 bv0 = *(const float4*)(Bp + (long)kt * N);
        const float4 bv1 = *(const float4*)(Bp + (long)kt * N + 64);
        As[acol8 + 0][arow] = av0.x;
        As[acol8 + 1][arow] = av0.y;
        As[acol8 + 2][arow] = av0.z;
        As[acol8 + 3][arow] = av0.w;
        As[acol8 + 4][arow] = av1.x;
        As[acol8 + 5][arow] = av1.y;
        As[acol8 + 6][arow] = av1.z;
        As[acol8 + 7][arow] = av1.w;
        *(float4*)&Bs[brow][bcol] = bv0;
        *(float4*)&Bs[brow][bcol + 64] = bv1;
        __syncthreads();
#pragma unroll
        for (int k = 0; k < 16; ++k) {
            const float4 a0 = *(const float4*)&As[k][ty * 4];
            const float4 a1 = *(const float4*)&As[k][ty * 4 + 64];
            const float4 b0 = *(const float4*)&Bs[k][tx * 4];
            const float4 b1 = *(const float4*)&Bs[k][tx * 4 + 64];
            const float ar[8] = {a0.x, a0.y, a0.z, a0.w, a1.x, a1.y, a1.z, a1.w};
            const float br[8] = {b0.x, b0.y, b0.z, b0.w, b1.x, b1.y, b1.z, b1.w};
#pragma unroll
            for (int i = 0; i < 8; ++i)
#pragma unroll
                for (int j = 0; j < 8; ++j)
                    acc[i][j] = fmaf(ar[i], br[j], acc[i][j]);
        }
        __syncthreads();
    }

    float4 bb0 = make_float4(0.f, 0.f, 0.f, 0.f);
    float4 bb1 = bb0;
    if (bias) {
        bb0 = *(const float4*)(bias + bx * 128 + tx * 4);
        bb1 = *(const float4*)(bias + bx * 128 + tx * 4 + 64);
    }
#pragma unroll
    for (int ih = 0; ih < 2; ++ih) {
#pragma unroll
        for (int i = 0; i < 4; ++i) {
            const int row = by * 128 + ty * 4 + ih * 64 + i;
            float* crow = C + (long)row * N + bx * 128;
            float4 o0, o1;
            o0.x = acc[ih * 4 + i][0] + bb0.x;
            o0.y = acc[ih * 4 + i][1] + bb0.y;
            o0.z = acc[ih * 4 + i][2] + bb0.z;
            o0.w = acc[ih * 4 + i][3] + bb0.w;
            o1.x = acc[ih * 4 + i][4] + bb1.x;
            o1.y = acc[ih * 4 + i][5] + bb1.y;
            o1.z = acc[ih * 4 + i][6] + bb1.z;
            o1.w = acc[ih * 4 + i][7] + bb1.w;
            *(float4*)(crow + tx * 4) = o0;
            *(float4*)(crow + tx * 4 + 64) = o1;
        }
    }
}

// ---------------------------------------------------------------------------
// Fused KNN attention. One wave per query. Phase 1: lane=(h,k) one q.k dot
// (float4 loads), shfl softmax over k-groups of 8. Phase 2: lane owns 8
// CONSECUTIVE dims (within one head) -> v reads are 2 float4 per neighbor
// (4x fewer VMEM insts than scalar gather); writes f32 in-place over qall.
// ---------------------------------------------------------------------------
__global__ __launch_bounds__(256) void attn_kernel(const float* qall,
                                                   const float* __restrict__ kvall,
                                                   const int* __restrict__ idxp,
                                                   float* outp)
{
    __shared__ float attn_s[4][8][8];
    const int wave = threadIdx.x >> 6;
    const int lane = threadIdx.x & 63;
    const int g = blockIdx.x * 4 + wave;     // query 0..16383
    const int b = g >> 13;
    const int* myidx = idxp + (long)g * 8;

    {
        const int h = lane >> 3;
        const int k = lane & 7;
        const int j = myidx[k];
        const float* qrow = qall + (long)g * 512 + h * 64;
        const float* krow = kvall + ((long)(b * N_PTS + j)) * 1024 + h * 64;

        float dot = 0.f;
#pragma unroll
        for (int d4 = 0; d4 < 64; d4 += 4) {
            const float4 qv = *(const float4*)(qrow + d4);
            const float4 kv = *(const float4*)(krow + d4);
            dot = fmaf(qv.x, kv.x, dot);
            dot = fmaf(qv.y, kv.y, dot);
            dot = fmaf(qv.z, kv.z, dot);
            dot = fmaf(qv.w, kv.w, dot);
        }
        dot *= 0.125f;                        // DH^-0.5

        float m = dot;
#pragma unroll
        for (int off = 1; off < 8; off <<= 1)
            m = fmaxf(m, __shfl_xor(m, off, 8));
        const float e = __expf(dot - m);
        float ssum = e;
#pragma unroll
        for (int off = 1; off < 8; off <<= 1)
            ssum += __shfl_xor(ssum, off, 8);
        attn_s[wave][h][k] = e / ssum;
    }
    __syncthreads();                          // drains q reads before aliased writes

    const int d8 = lane * 8;                  // 8 consecutive dims, one head
    const int h2 = lane >> 3;
    float o0 = 0.f, o1 = 0.f, o2 = 0.f, o3 = 0.f;
    float o4 = 0.f, o5 = 0.f, o6 = 0.f, o7 = 0.f;
#pragma unroll
    for (int kk = 0; kk < 8; ++kk) {
        const int jj = myidx[kk];
        const float w = attn_s[wave][h2][kk];
        const float* vrow = kvall + ((long)(b * N_PTS + jj)) * 1024 + 512 + d8;
        const float4 v0 = *(const float4*)(vrow);
        const float4 v1 = *(const float4*)(vrow + 4);
        o0 = fmaf(w, v0.x, o0); o1 = fmaf(w, v0.y, o1);
        o2 = fmaf(w, v0.z, o2); o3 = fmaf(w, v0.w, o3);
        o4 = fmaf(w, v1.x, o4); o5 = fmaf(w, v1.y, o5);
        o6 = fmaf(w, v1.z, o6); o7 = fmaf(w, v1.w, o7);
    }
    float* orow = outp + (long)g * 512 + d8;
    *(float4*)(orow)     = make_float4(o0, o1, o2, o3);
    *(float4*)(orow + 4) = make_float4(o4, o5, o6, o7);
}

// ---------------------------------------------------------------------------
extern "C" void kernel_launch(void* const* d_in, const int* in_sizes, int n_in,
                              void* d_out, int out_size, void* d_ws, size_t ws_size,
                              hipStream_t stream)
{
    const float* x    = (const float*)d_in[0];  // [2,8192,256]
    const float* pos  = (const float*)d_in[1];  // [2,8192,3]
    const float* Wq   = (const float*)d_in[2];  // [256,512]
    const float* Wkv  = (const float*)d_in[3];  // [256,1024]
    const float* Wout = (const float*)d_in[4];  // [512,256]
    const float* bout = (const float*)d_in[5];  // [256]
    float* out = (float*)d_out;                 // [2,8192,256] f32

    // workspace layout (96.5 MB total):
    int*   idxp  = (int*)d_ws;                       // 131072 ints
    float* qall  = (float*)d_ws + 131072;            // 16384x512 f32 (32 MB)
    float* kvall = qall + (long)16384 * 512;         // 16384x1024 f32 (64 MB)
    // knn scratch (16.8 MB) inside kvall region; consumed by merge before kv-gemm
    unsigned long long* partial = (unsigned long long*)kvall;

    const int M = 16384;

    knn_partial<<<1024, 256, 0, stream>>>(pos, partial);
    knn_merge<<<64, 256, 0, stream>>>(partial, idxp);
    gemm_bf16<0><<<dim3(512 / 128, M / 128), 256, 0, stream>>>(x, Wq, qall, 512, 256, 256);
    gemm_bf16<0><<<dim3(1024 / 128, M / 128), 256, 0, stream>>>(x, Wkv, kvall, 1024, 256, 256);
    attn_kernel<<<M / 4, 256, 0, stream>>>(qall, kvall, idxp, qall);   // in-place
    sgemm128<<<dim3(256 / 128, M / 128), 256, 0, stream>>>(qall, Wout, bout, out, M, 256, 512);
}

// Round 5
// 321.464 us; speedup vs baseline: 1.8501x; 1.2598x over previous
//
#include <hip/hip_runtime.h>
#include <hip/hip_bf16.h>

#define N_PTS 8192
#define KNN 8

typedef __attribute__((ext_vector_type(8))) short short8;
typedef __attribute__((ext_vector_type(4))) float float4v;

// f32 -> bf16 round-to-nearest-even (finite inputs only)
static __device__ __forceinline__ short f2bf(float f) {
    unsigned u = __float_as_uint(f);
    unsigned r = (u + 0x7FFFu + ((u >> 16) & 1u)) >> 16;
    return (short)r;
}
static __device__ __forceinline__ float bf2f(short s) {
    return __uint_as_float(((unsigned)(unsigned short)s) << 16);
}

// ---------------------------------------------------------------------------
// KNN stage 1: threshold-first exact top-8 (see round-4 notes). One query per
// thread, candidates staged in LDS SoA, branchless bucket minima + collect.
// ---------------------------------------------------------------------------
__global__ __launch_bounds__(256) void knn_partial(const float* __restrict__ pos,
                                                   unsigned long long* __restrict__ partial)
{
    __shared__ float sx[512], sy[512], sz[512];
    __shared__ unsigned long long buf[256][17];

    const int tid = threadIdx.x;
    const int p   = blockIdx.x & 15;
    const int qg  = blockIdx.x >> 4;
    const int batch = qg >> 5;
    const int q_in_b = (qg & 31) * 256 + tid;
    const float* bpos = pos + (long)batch * N_PTS * 3;

    if (tid < 128) {
        const float* src = bpos + (p * 512 + tid * 4) * 3;
        const float4 f0 = *(const float4*)(src);
        const float4 f1 = *(const float4*)(src + 4);
        const float4 f2 = *(const float4*)(src + 8);
        const int c0 = tid * 4;
        *(float4*)&sx[c0] = make_float4(f0.x, f0.w, f1.z, f2.y);
        *(float4*)&sy[c0] = make_float4(f0.y, f1.x, f1.w, f2.z);
        *(float4*)&sz[c0] = make_float4(f0.z, f1.y, f2.x, f2.w);
    }
    __syncthreads();

    const float qx = bpos[q_in_b * 3 + 0];
    const float qy = bpos[q_in_b * 3 + 1];
    const float qz = bpos[q_in_b * 3 + 2];

    const float4* vx = (const float4*)sx;
    const float4* vy = (const float4*)sy;
    const float4* vz = (const float4*)sz;

    float bmin[32];
#pragma unroll
    for (int j = 0; j < 32; ++j) bmin[j] = 3.0e38f;

    for (int base = 0; base < 128; base += 8) {
#pragma unroll
        for (int g = 0; g < 8; ++g) {
            const float4 cx = vx[base + g];
            const float4 cy = vy[base + g];
            const float4 cz = vz[base + g];
            { const float dx = cx.x - qx, dy = cy.x - qy, dz = cz.x - qz;
              bmin[g*4+0] = fminf(bmin[g*4+0], fmaf(dx, dx, fmaf(dy, dy, dz*dz))); }
            { const float dx = cx.y - qx, dy = cy.y - qy, dz = cz.y - qz;
              bmin[g*4+1] = fminf(bmin[g*4+1], fmaf(dx, dx, fmaf(dy, dy, dz*dz))); }
            { const float dx = cx.z - qx, dy = cy.z - qy, dz = cz.z - qz;
              bmin[g*4+2] = fminf(bmin[g*4+2], fmaf(dx, dx, fmaf(dy, dy, dz*dz))); }
            { const float dx = cx.w - qx, dy = cy.w - qy, dz = cz.w - qz;
              bmin[g*4+3] = fminf(bmin[g*4+3], fmaf(dx, dx, fmaf(dy, dy, dz*dz))); }
        }
    }

    float t8[8];
#pragma unroll
    for (int j = 0; j < 8; ++j) t8[j] = 3.0e38f;
#pragma unroll
    for (int i = 0; i < 32; ++i) {
        float x = bmin[i];
#pragma unroll
        for (int j = 0; j < 8; ++j) {
            const float lo = fminf(t8[j], x);
            const float hi = fmaxf(t8[j], x);
            t8[j] = lo; x = hi;
        }
    }
    const float t = t8[7];

    int cnt = 0;
    for (int base = 0; base < 128; ++base) {
        const float4 cx = vx[base];
        const float4 cy = vy[base];
        const float4 cz = vz[base];
#pragma unroll
        for (int j = 0; j < 4; ++j) {
            const float ccx = j == 0 ? cx.x : j == 1 ? cx.y : j == 2 ? cx.z : cx.w;
            const float ccy = j == 0 ? cy.x : j == 1 ? cy.y : j == 2 ? cy.z : cy.w;
            const float ccz = j == 0 ? cz.x : j == 1 ? cz.y : j == 2 ? cz.z : cz.w;
            const float dx = ccx - qx, dy = ccy - qy, dz = ccz - qz;
            const float d2 = fmaf(dx, dx, fmaf(dy, dy, dz * dz));
            if (d2 <= t) {
                buf[tid][cnt < 16 ? cnt : 16] =
                    ((unsigned long long)__float_as_uint(d2) << 32)
                    | (unsigned)(p * 512 + base * 4 + j);
                ++cnt;
            }
        }
    }

    unsigned long long best[8];
#pragma unroll
    for (int j = 0; j < 8; ++j) best[j] = ~0ULL;

    if (cnt <= 16) {
        for (int u = 0; u < cnt; ++u) {
            unsigned long long x = buf[tid][u];
#pragma unroll
            for (int j = 0; j < 8; ++j) {
                const unsigned long long lo = x < best[j] ? x : best[j];
                const unsigned long long hi = x < best[j] ? best[j] : x;
                best[j] = lo; x = hi;
            }
        }
    } else {
        for (int i = 0; i < 512; ++i) {
            const float dx = sx[i] - qx, dy = sy[i] - qy, dz = sz[i] - qz;
            const float d2 = fmaf(dx, dx, fmaf(dy, dy, dz * dz));
            unsigned long long x =
                ((unsigned long long)__float_as_uint(d2) << 32)
                | (unsigned)(p * 512 + i);
            if (x < best[7]) {
#pragma unroll
                for (int j = 0; j < 8; ++j) {
                    const unsigned long long lo = x < best[j] ? x : best[j];
                    const unsigned long long hi = x < best[j] ? best[j] : x;
                    best[j] = lo; x = hi;
                }
            }
        }
    }

    const long qglob = (long)batch * N_PTS + q_in_b;
#pragma unroll
    for (int j = 0; j < 8; ++j)
        partial[(long)(p * 8 + j) * 16384 + qglob] = best[j];
}

__global__ __launch_bounds__(256) void knn_merge(const unsigned long long* __restrict__ partial,
                                                 int* __restrict__ idxo)
{
    const int q = blockIdx.x * 256 + threadIdx.x;
    unsigned long long best[8];
#pragma unroll
    for (int j = 0; j < 8; ++j) best[j] = ~0ULL;
    for (int s = 0; s < 128; ++s) {
        unsigned long long x = partial[(long)s * 16384 + q];
        if (x < best[7]) {
#pragma unroll
            for (int j = 0; j < 8; ++j) {
                const unsigned long long lo = x < best[j] ? x : best[j];
                const unsigned long long hi = x < best[j] ? best[j] : x;
                best[j] = lo; x = hi;
            }
        }
    }
#pragma unroll
    for (int j = 0; j < 8; ++j)
        idxo[(long)q * 8 + j] = (int)(best[j] & 0xFFFFFFFFu);
}

// ---------------------------------------------------------------------------
// bf16 MFMA GEMM. ABF16: A is bf16 (else f32, converted in staging).
// OUTBF16: C stored bf16 RNE (else f32 + optional bias).
// 128x128 tile, BK=32, 4 waves 2x2, 16x16x32 MFMA (layouts per m89/m91).
// ---------------------------------------------------------------------------
template<int ABF16, int OUTBF16>
__global__ __launch_bounds__(256) void gemm_bf16(const void* __restrict__ A_,
                                                 const float* __restrict__ B,
                                                 const float* __restrict__ bias,
                                                 void* __restrict__ C_,
                                                 int N, int Kd, int lda)
{
    __shared__ short As[4][128][8];
    __shared__ short Bs[4][128][8];

    const int tid  = threadIdx.x;
    const int lane = tid & 63;
    const int wv   = tid >> 6;
    const int quad = lane >> 4;
    const int l15  = lane & 15;
    const int m0 = blockIdx.y * 128;
    const int n0 = blockIdx.x * 128;
    const int mh = (wv & 1) * 64, nh = (wv >> 1) * 64;

    const int sm  = tid >> 1;
    const int skh = (tid & 1) * 16;
    const int sn  = tid & 127;
    const int skb = (tid >> 7) * 16;

    float4v acc[4][4];
#pragma unroll
    for (int i = 0; i < 4; ++i)
#pragma unroll
        for (int j = 0; j < 4; ++j) acc[i][j] = (float4v)(0.f);

    for (int k0 = 0; k0 < Kd; k0 += 32) {
        if (ABF16) {
            const short* Ab = (const short*)A_;
            const short8* src = (const short8*)(Ab + (long)(m0 + sm) * lda + k0 + skh);
            *(short8*)&As[skh >> 3][sm][0] = src[0];
            *(short8*)&As[(skh >> 3) + 1][sm][0] = src[1];
        } else {
            const float* Af = (const float*)A_;
            const float* ap = Af + (long)(m0 + sm) * lda + k0 + skh;
            const float4 a0 = *(const float4*)ap;
            const float4 a1 = *(const float4*)(ap + 4);
            const float4 a2 = *(const float4*)(ap + 8);
            const float4 a3 = *(const float4*)(ap + 12);
            short8 w0 = {f2bf(a0.x), f2bf(a0.y), f2bf(a0.z), f2bf(a0.w),
                         f2bf(a1.x), f2bf(a1.y), f2bf(a1.z), f2bf(a1.w)};
            short8 w1 = {f2bf(a2.x), f2bf(a2.y), f2bf(a2.z), f2bf(a2.w),
                         f2bf(a3.x), f2bf(a3.y), f2bf(a3.z), f2bf(a3.w)};
            *(short8*)&As[skh >> 3][sm][0] = w0;
            *(short8*)&As[(skh >> 3) + 1][sm][0] = w1;
        }
        {
            const float* bp = B + (long)(k0 + skb) * N + n0 + sn;
            short v[16];
#pragma unroll
            for (int kk = 0; kk < 16; ++kk)
                v[kk] = f2bf(bp[(long)kk * N]);
            short8 w0 = {v[0], v[1], v[2], v[3], v[4], v[5], v[6], v[7]};
            short8 w1 = {v[8], v[9], v[10], v[11], v[12], v[13], v[14], v[15]};
            *(short8*)&Bs[skb >> 3][sn][0] = w0;
            *(short8*)&Bs[(skb >> 3) + 1][sn][0] = w1;
        }
        __syncthreads();

        short8 af[4], bfv[4];
#pragma unroll
        for (int i = 0; i < 4; ++i)
            af[i] = *(const short8*)&As[quad][mh + i * 16 + l15][0];
#pragma unroll
        for (int j = 0; j < 4; ++j)
            bfv[j] = *(const short8*)&Bs[quad][nh + j * 16 + l15][0];
#pragma unroll
        for (int i = 0; i < 4; ++i)
#pragma unroll
            for (int j = 0; j < 4; ++j)
                acc[i][j] = __builtin_amdgcn_mfma_f32_16x16x32_bf16(af[i], bfv[j], acc[i][j], 0, 0, 0);
        __syncthreads();
    }

#pragma unroll
    for (int i = 0; i < 4; ++i)
#pragma unroll
        for (int j = 0; j < 4; ++j) {
            const int col = n0 + nh + j * 16 + l15;
            const float bb = (!OUTBF16 && bias) ? bias[col] : 0.f;
#pragma unroll
            for (int r = 0; r < 4; ++r) {
                const int row = m0 + mh + i * 16 + quad * 4 + r;
                if (OUTBF16) {
                    ((short*)C_)[(long)row * N + col] = f2bf(acc[i][j][r]);
                } else {
                    ((float*)C_)[(long)row * N + col] = acc[i][j][r] + bb;
                }
            }
        }
}

// ---------------------------------------------------------------------------
// Fused KNN attention, bf16 storage / f32 math. One wave per query.
// Phase 1: lane=(h,k), 64-dot via short8 loads, shfl softmax over k-groups.
// Phase 2: lane owns 8 consecutive dims of one head; one short8 per neighbor.
// In-place over q buffer (each query's q row read only by its own wave,
// fully consumed before the barrier).
// ---------------------------------------------------------------------------
__global__ __launch_bounds__(256) void attn_kernel(const short* qall,
                                                   const short* __restrict__ kvall,
                                                   const int* __restrict__ idxp,
                                                   short* outp)
{
    __shared__ float attn_s[4][8][8];
    const int wave = threadIdx.x >> 6;
    const int lane = threadIdx.x & 63;
    const int g = blockIdx.x * 4 + wave;
    const int b = g >> 13;
    const int* myidx = idxp + (long)g * 8;

    {
        const int h = lane >> 3;
        const int k = lane & 7;
        const int j = myidx[k];
        const short8* qrow = (const short8*)(qall + (long)g * 512 + h * 64);
        const short8* krow = (const short8*)(kvall + ((long)(b * N_PTS + j)) * 1024 + h * 64);

        float dot = 0.f;
#pragma unroll
        for (int c = 0; c < 8; ++c) {
            const short8 qv = qrow[c];
            const short8 kv = krow[c];
#pragma unroll
            for (int e = 0; e < 8; ++e)
                dot = fmaf(bf2f(qv[e]), bf2f(kv[e]), dot);
        }
        dot *= 0.125f;

        float m = dot;
#pragma unroll
        for (int off = 1; off < 8; off <<= 1)
            m = fmaxf(m, __shfl_xor(m, off, 8));
        const float e = __expf(dot - m);
        float ssum = e;
#pragma unroll
        for (int off = 1; off < 8; off <<= 1)
            ssum += __shfl_xor(ssum, off, 8);
        attn_s[wave][h][k] = e / ssum;
    }
    __syncthreads();                          // drains q reads before aliased writes

    const int d8 = lane * 8;
    const int h2 = lane >> 3;
    float o[8] = {0.f, 0.f, 0.f, 0.f, 0.f, 0.f, 0.f, 0.f};
#pragma unroll
    for (int kk = 0; kk < 8; ++kk) {
        const int jj = myidx[kk];
        const float w = attn_s[wave][h2][kk];
        const short8 v = *(const short8*)(kvall + ((long)(b * N_PTS + jj)) * 1024 + 512 + d8);
#pragma unroll
        for (int e = 0; e < 8; ++e)
            o[e] = fmaf(w, bf2f(v[e]), o[e]);
    }
    short8 ov = {f2bf(o[0]), f2bf(o[1]), f2bf(o[2]), f2bf(o[3]),
                 f2bf(o[4]), f2bf(o[5]), f2bf(o[6]), f2bf(o[7])};
    *(short8*)(outp + (long)g * 512 + d8) = ov;
}

// ---------------------------------------------------------------------------
extern "C" void kernel_launch(void* const* d_in, const int* in_sizes, int n_in,
                              void* d_out, int out_size, void* d_ws, size_t ws_size,
                              hipStream_t stream)
{
    const float* x    = (const float*)d_in[0];  // [2,8192,256]
    const float* pos  = (const float*)d_in[1];  // [2,8192,3]
    const float* Wq   = (const float*)d_in[2];  // [256,512]
    const float* Wkv  = (const float*)d_in[3];  // [256,1024]
    const float* Wout = (const float*)d_in[4];  // [512,256]
    const float* bout = (const float*)d_in[5];  // [256]
    float* out = (float*)d_out;                 // [2,8192,256] f32

    // workspace: idx (512KB) | qall bf16 (16MB) | kvall bf16 (32MB)
    int*   idxp = (int*)d_ws;
    short* qall = (short*)((char*)d_ws + (1 << 19));
    short* kvall = qall + (long)16384 * 512;
    // knn scratch (16.8 MB) in kvall region; consumed by merge before kv-gemm
    unsigned long long* partial = (unsigned long long*)kvall;

    const int M = 16384;

    knn_partial<<<1024, 256, 0, stream>>>(pos, partial);
    knn_merge<<<64, 256, 0, stream>>>(partial, idxp);
    gemm_bf16<0, 1><<<dim3(512 / 128, M / 128), 256, 0, stream>>>(x, Wq, nullptr, qall, 512, 256, 256);
    gemm_bf16<0, 1><<<dim3(1024 / 128, M / 128), 256, 0, stream>>>(x, Wkv, nullptr, kvall, 1024, 256, 256);
    attn_kernel<<<M / 4, 256, 0, stream>>>(qall, kvall, idxp, qall);   // in-place
    gemm_bf16<1, 0><<<dim3(256 / 128, M / 128), 256, 0, stream>>>(qall, Wout, bout, out, 256, 512, 512);
}